// Round 5
// baseline (363.108 us; speedup 1.0000x reference)
//
#include <hip/hip_runtime.h>
#include <hip/hip_cooperative_groups.h>

namespace cg = cooperative_groups;

// Problem constants (from reference)
#define NB 4
#define S_OUT 32                                  // 128 / 4 (two 2x pools fused)
#define NC 64
#define OUT_CELLS (NB * S_OUT * S_OUT * S_OUT)    // 131072
#define OUT_ELEMS (OUT_CELLS * NC)                // 8388608 floats
#define CAP 16                                    // slots per cell (lambda=3.8, P(n>16)~7e-7)
#define OVF_CAP 65536
#define GRID_BLOCKS 1024                          // 4 blocks/CU -> co-resident, safe
#define BLOCK 256

__device__ __forceinline__ void atomicMaxFloat(float* addr, float val) {
    unsigned* ua = (unsigned*)addr;
    unsigned old = *ua;
    while (true) {
        float f = __uint_as_float(old);
        if (f >= val) break;
        unsigned assumed = old;
        old = atomicCAS(ua, assumed, __float_as_uint(val));
        if (old == assumed) break;
    }
}

// One cooperative kernel: zero -> fill -> gather -> overflow, grid.sync between.
__global__ __launch_bounds__(BLOCK) void fused_kernel(
        const float* __restrict__ features,
        const int4* __restrict__ coors,
        int* __restrict__ cnt,
        int* __restrict__ list,
        int* __restrict__ ovf_cnt,
        int* __restrict__ ovf,
        float* __restrict__ out,
        int n_pts) {
    cg::grid_group grid = cg::this_grid();
    const int tid = blockIdx.x * BLOCK + threadIdx.x;
    const int nthreads = gridDim.x * BLOCK;

    // ---- phase 0: zero the counters ----
    for (int i = tid; i < OUT_CELLS; i += nthreads) cnt[i] = 0;
    if (tid == 0) *ovf_cnt = 0;
    grid.sync();

    // ---- phase 1: bin points into per-cell lists ----
    for (int p = tid; p < n_pts; p += nthreads) {
        int4 co = coors[p];
        int cell = ((co.x * S_OUT + (co.y >> 2)) * S_OUT + (co.z >> 2)) * S_OUT + (co.w >> 2);
        int slot = atomicAdd(&cnt[cell], 1);
        if (slot < CAP) {
            list[cell * CAP + slot] = p;
        } else {
            int o = atomicAdd(ovf_cnt, 1);
            if (o < OVF_CAP) ovf[o] = p;
        }
    }
    grid.sync();

    // ---- phase 2: gather max, 4 cells per wave (16-lane group per cell) ----
    // lane layout: group q = lane>>4 owns cell cell0+q; lane holds channel
    // quad cl = (lane&15)*4; slot s of group q sits in lane (lane&48)+s.
    const int lane = threadIdx.x & 63;
    const int wid = tid >> 6;
    const int nwaves = nthreads >> 6;
    const int cl = (lane & 15) << 2;
    const int sbase = lane & 48;
    for (int g = wid; g < OUT_CELLS / 4; g += nwaves) {
        int cell0 = g << 2;
        int n = cnt[cell0 + (lane >> 4)];      // uniform within 16-lane group
        int m = n < CAP ? n : CAP;
        int pl = list[(size_t)cell0 * CAP + lane];   // coalesced: 4 cells x 16 slots
        float4 acc = make_float4(-INFINITY, -INFINITY, -INFINITY, -INFINITY);
        #pragma unroll
        for (int s = 0; s < 8; ++s) {
            int p = __shfl(pl, sbase + s);
            bool v = s < m;
            int ps = v ? p : 0;                // invalid -> row 0 (cache-hot dummy)
            const float4 f = *(const float4*)(features + (size_t)ps * NC + cl);
            if (v) {
                acc.x = fmaxf(acc.x, f.x); acc.y = fmaxf(acc.y, f.y);
                acc.z = fmaxf(acc.z, f.z); acc.w = fmaxf(acc.w, f.w);
            }
        }
        if (m > 8) {                           // rare tail (P ~ 1.3% per cell)
            for (int s = 8; s < m; ++s) {
                int p = __shfl(pl, sbase + s);
                const float4 f = *(const float4*)(features + (size_t)p * NC + cl);
                acc.x = fmaxf(acc.x, f.x); acc.y = fmaxf(acc.y, f.y);
                acc.z = fmaxf(acc.z, f.z); acc.w = fmaxf(acc.w, f.w);
            }
        }
        if (n == 0) acc = make_float4(0.f, 0.f, 0.f, 0.f);
        *(float4*)(out + (size_t)cell0 * NC + (size_t)lane * 4) = acc;
    }
    grid.sync();

    // ---- phase 3: fold overflow points (expected ~0) ----
    int novf = *ovf_cnt;
    if (novf > OVF_CAP) novf = OVF_CAP;
    if (novf > 0) {
        for (int i = wid; i < novf; i += nwaves) {
            int p = ovf[i];
            int4 co = coors[p];
            int cell = ((co.x * S_OUT + (co.y >> 2)) * S_OUT + (co.z >> 2)) * S_OUT + (co.w >> 2);
            atomicMaxFloat(&out[(size_t)cell * NC + lane], features[(size_t)p * NC + lane]);
        }
    }
}

// ---------- fallback path (R1's working atomicMax scatter) ----------

__device__ __forceinline__ unsigned flip_f(float f) {
    unsigned u = __float_as_uint(f);
    return (u & 0x80000000u) ? ~u : (u | 0x80000000u);
}
__device__ __forceinline__ float unflip_f(unsigned u) {
    unsigned v = (u & 0x80000000u) ? (u & 0x7FFFFFFFu) : ~u;
    return __uint_as_float(v);
}

__global__ void init_kernel(uint4* __restrict__ out4, int n4) {
    int i = blockIdx.x * blockDim.x + threadIdx.x;
    int stride = gridDim.x * blockDim.x;
    uint4 z = make_uint4(0u, 0u, 0u, 0u);
    for (; i < n4; i += stride) out4[i] = z;
}

__global__ void scatter_kernel(const float* __restrict__ features,
                               const int4* __restrict__ coors,
                               unsigned* __restrict__ acc, int n_pts) {
    int gid = blockIdx.x * blockDim.x + threadIdx.x;
    int p = gid >> 6;
    int c = threadIdx.x & 63;
    if (p >= n_pts) return;
    int4 co = coors[p];
    int cell = ((co.x * S_OUT + (co.y >> 2)) * S_OUT + (co.z >> 2)) * S_OUT + (co.w >> 2);
    atomicMax(acc + (size_t)cell * NC + c, flip_f(features[(size_t)p * NC + c]));
}

__global__ void finalize_kernel(unsigned* __restrict__ acc, int n) {
    int i = blockIdx.x * blockDim.x + threadIdx.x;
    int stride = gridDim.x * blockDim.x;
    for (; i < n; i += stride) {
        unsigned u = acc[i];
        ((float*)acc)[i] = (u == 0u) ? 0.0f : unflip_f(u);
    }
}

extern "C" void kernel_launch(void* const* d_in, const int* in_sizes, int n_in,
                              void* d_out, int out_size, void* d_ws, size_t ws_size,
                              hipStream_t stream) {
    const float* features = (const float*)d_in[0];
    const int4*  coors    = (const int4*)d_in[1];
    int n_pts = in_sizes[0] / NC;   // 500000

    // workspace layout
    const size_t off_cnt  = 0;
    const size_t cnt_b    = (size_t)OUT_CELLS * 4;             // 524288
    const size_t off_ovfc = cnt_b;                             // 4B counter
    const size_t off_ovf  = off_ovfc + 256;
    const size_t off_list = off_ovf + (size_t)OVF_CAP * 4;
    const size_t need     = off_list + (size_t)OUT_CELLS * CAP * 4;   // ~9 MB

    if (ws_size >= need) {
        char* ws = (char*)d_ws;
        int* cnt     = (int*)(ws + off_cnt);
        int* ovf_cnt = (int*)(ws + off_ovfc);
        int* ovf     = (int*)(ws + off_ovf);
        int* list    = (int*)(ws + off_list);
        float* out   = (float*)d_out;

        void* args[] = { (void*)&features, (void*)&coors, (void*)&cnt,
                         (void*)&list, (void*)&ovf_cnt, (void*)&ovf,
                         (void*)&out, (void*)&n_pts };
        hipLaunchCooperativeKernel((void*)fused_kernel,
                                   dim3(GRID_BLOCKS), dim3(BLOCK),
                                   args, 0, stream);
    } else {
        // fallback: R1 atomic scatter path
        unsigned* acc = (unsigned*)d_out;
        init_kernel<<<2048, 256, 0, stream>>>((uint4*)d_out, OUT_ELEMS / 4);
        int grid = (n_pts * 64 + 255) / 256;
        scatter_kernel<<<grid, 256, 0, stream>>>(features, coors, acc, n_pts);
        finalize_kernel<<<2048, 256, 0, stream>>>(acc, OUT_ELEMS);
    }
}

// Round 7
// 63.948 us; speedup vs baseline: 5.6781x; 5.6781x over previous
//
#include <hip/hip_runtime.h>

// Problem constants (from reference)
#define NB 4
#define S_OUT 32                                  // 128 / 4 (two 2x pools fused)
#define NC 64
#define OUT_CELLS (NB * S_OUT * S_OUT * S_OUT)    // 131072
#define OUT_ELEMS (OUT_CELLS * NC)                // 8388608 floats
#define NGROUPS (OUT_CELLS / 4)                   // 32768 (4 cells per wave)
#define CAP 16                                    // slots per cell (lambda=3.8, P(n>16)~7e-7)
#define OVF_CAP 65536

typedef float floatx4 __attribute__((ext_vector_type(4)));   // native vec for nt-store

// ---------- gather path ----------

__global__ void fill_kernel(const int4* __restrict__ coors,
                            int* __restrict__ cnt,
                            int* __restrict__ list,
                            int* __restrict__ ovf_cnt,
                            int* __restrict__ ovf,
                            int n_pts) {
    int p = blockIdx.x * blockDim.x + threadIdx.x;
    if (p >= n_pts) return;
    int4 co = coors[p];
    int cell = ((co.x * S_OUT + (co.y >> 2)) * S_OUT + (co.z >> 2)) * S_OUT + (co.w >> 2);
    int slot = atomicAdd(&cnt[cell], 1);
    if (slot < CAP) {
        list[cell * CAP + slot] = p;
    } else {
        int o = atomicAdd(ovf_cnt, 1);
        if (o < OVF_CAP) ovf[o] = p;   // owner group folds these in gather
    }
}

// 4 cells per wave; 16-lane group q = lane>>4 owns cell (g*4+q); lane holds
// channel quad cl=(lane&15)*4. Grid-stride over groups with next-iteration
// cnt/list prefetch (hides the list->shfl->load chain). Overflow (n>CAP,
// ultra-rare) folded by the owner group via a scan of the ovf array.
__global__ __launch_bounds__(256) void gather_kernel(
        const float* __restrict__ features,
        const int4* __restrict__ coors,
        const int* __restrict__ cnt,
        const int* __restrict__ list,
        const int* __restrict__ ovf_cnt,
        const int* __restrict__ ovf,
        float* __restrict__ out) {
    const int lane  = threadIdx.x & 63;
    const int wid   = (blockIdx.x * blockDim.x + threadIdx.x) >> 6;
    const int nw    = (gridDim.x * blockDim.x) >> 6;
    const int cl    = (lane & 15) << 2;    // channel quad base
    const int sbase = lane & 48;           // group's slot base lane
    const int qsel  = lane >> 4;           // group index 0..3

    int g = wid;
    if (g >= NGROUPS) return;

    // prefetch first group's metadata
    int n_pf  = cnt[(g << 2) + qsel];
    int pl_pf = list[((size_t)g << 6) + lane];   // 4 cells x 16 slots = 64 dwords

    while (true) {
        int n  = n_pf;
        int pl = pl_pf;
        int gn = g + nw;
        if (gn < NGROUPS) {                       // prefetch next iteration
            n_pf  = cnt[(gn << 2) + qsel];
            pl_pf = list[((size_t)gn << 6) + lane];
        }

        int m = n < CAP ? n : CAP;
        float4 acc = make_float4(-INFINITY, -INFINITY, -INFINITY, -INFINITY);

        #pragma unroll
        for (int s = 0; s < 8; ++s) {
            int p = __shfl(pl, sbase + s);
            bool v = s < m;
            int ps = v ? p : 0;                   // invalid -> row 0 (cache-hot dummy)
            const float4 f = *(const float4*)(features + (size_t)ps * NC + cl);
            if (v) {
                acc.x = fmaxf(acc.x, f.x); acc.y = fmaxf(acc.y, f.y);
                acc.z = fmaxf(acc.z, f.z); acc.w = fmaxf(acc.w, f.w);
            }
        }
        if (m > 8) {                              // uncommon tail (P ~ 1.3%)
            for (int s = 8; s < m; ++s) {
                int p = __shfl(pl, sbase + s);
                const float4 f = *(const float4*)(features + (size_t)p * NC + cl);
                acc.x = fmaxf(acc.x, f.x); acc.y = fmaxf(acc.y, f.y);
                acc.z = fmaxf(acc.z, f.z); acc.w = fmaxf(acc.w, f.w);
            }
        }
        if (__builtin_expect(__any(n > CAP), 0)) {   // owner-side overflow fold
            int mycell = (g << 2) + qsel;
            int novf = *ovf_cnt;
            if (novf > OVF_CAP) novf = OVF_CAP;
            for (int i = 0; i < novf; ++i) {
                int p = ovf[i];                   // broadcast load
                int4 co = coors[p];
                int cellp = ((co.x * S_OUT + (co.y >> 2)) * S_OUT + (co.z >> 2)) * S_OUT + (co.w >> 2);
                if (n > CAP && cellp == mycell) {
                    const float4 f = *(const float4*)(features + (size_t)p * NC + cl);
                    acc.x = fmaxf(acc.x, f.x); acc.y = fmaxf(acc.y, f.y);
                    acc.z = fmaxf(acc.z, f.z); acc.w = fmaxf(acc.w, f.w);
                }
            }
        }
        if (n == 0) acc = make_float4(0.f, 0.f, 0.f, 0.f);
        floatx4 accv = { acc.x, acc.y, acc.z, acc.w };
        __builtin_nontemporal_store(accv, (floatx4*)(out + ((size_t)g << 8) + (size_t)lane * 4));

        if (gn >= NGROUPS) break;
        g = gn;
    }
}

// ---------- fallback path (R1's working atomicMax scatter) ----------

__device__ __forceinline__ unsigned flip_f(float f) {
    unsigned u = __float_as_uint(f);
    return (u & 0x80000000u) ? ~u : (u | 0x80000000u);
}
__device__ __forceinline__ float unflip_f(unsigned u) {
    unsigned v = (u & 0x80000000u) ? (u & 0x7FFFFFFFu) : ~u;
    return __uint_as_float(v);
}

__global__ void init_kernel(uint4* __restrict__ out4, int n4) {
    int i = blockIdx.x * blockDim.x + threadIdx.x;
    int stride = gridDim.x * blockDim.x;
    uint4 z = make_uint4(0u, 0u, 0u, 0u);
    for (; i < n4; i += stride) out4[i] = z;
}

__global__ void scatter_kernel(const float* __restrict__ features,
                               const int4* __restrict__ coors,
                               unsigned* __restrict__ acc, int n_pts) {
    int gid = blockIdx.x * blockDim.x + threadIdx.x;
    int p = gid >> 6;
    int c = threadIdx.x & 63;
    if (p >= n_pts) return;
    int4 co = coors[p];
    int cell = ((co.x * S_OUT + (co.y >> 2)) * S_OUT + (co.z >> 2)) * S_OUT + (co.w >> 2);
    atomicMax(acc + (size_t)cell * NC + c, flip_f(features[(size_t)p * NC + c]));
}

__global__ void finalize_kernel(unsigned* __restrict__ acc, int n) {
    int i = blockIdx.x * blockDim.x + threadIdx.x;
    int stride = gridDim.x * blockDim.x;
    for (; i < n; i += stride) {
        unsigned u = acc[i];
        ((float*)acc)[i] = (u == 0u) ? 0.0f : unflip_f(u);
    }
}

extern "C" void kernel_launch(void* const* d_in, const int* in_sizes, int n_in,
                              void* d_out, int out_size, void* d_ws, size_t ws_size,
                              hipStream_t stream) {
    const float* features = (const float*)d_in[0];
    const int4*  coors    = (const int4*)d_in[1];
    int n_pts = in_sizes[0] / NC;   // 500000

    // workspace layout
    const size_t off_cnt  = 0;
    const size_t cnt_b    = (size_t)OUT_CELLS * 4;             // 524288
    const size_t off_ovfc = cnt_b;                             // 4B counter
    const size_t off_ovf  = off_ovfc + 256;
    const size_t off_list = off_ovf + (size_t)OVF_CAP * 4;
    const size_t need     = off_list + (size_t)OUT_CELLS * CAP * 4;   // ~9 MB

    if (ws_size >= need) {
        char* ws = (char*)d_ws;
        int* cnt     = (int*)(ws + off_cnt);
        int* ovf_cnt = (int*)(ws + off_ovfc);
        int* ovf     = (int*)(ws + off_ovf);
        int* list    = (int*)(ws + off_list);
        float* out   = (float*)d_out;

        // zero counters (cnt region + overflow counter)
        (void)hipMemsetAsync(ws, 0, off_ovfc + 4, stream);

        // build per-cell point lists
        {
            int block = 256;
            int grid = (n_pts + block - 1) / block;
            fill_kernel<<<grid, block, 0, stream>>>(coors, cnt, list, ovf_cnt, ovf, n_pts);
        }
        // gather max (+ owner-side overflow fold): 4 cells/wave, prefetch pipeline
        {
            int block = 256;
            int grid = 2048;    // 8192 waves, 4 groups each
            gather_kernel<<<grid, block, 0, stream>>>(features, coors, cnt, list,
                                                      ovf_cnt, ovf, out);
        }
    } else {
        // fallback: R1 atomic scatter path
        unsigned* acc = (unsigned*)d_out;
        init_kernel<<<2048, 256, 0, stream>>>((uint4*)d_out, OUT_ELEMS / 4);
        int grid = (n_pts * 64 + 255) / 256;
        scatter_kernel<<<grid, 256, 0, stream>>>(features, coors, acc, n_pts);
        finalize_kernel<<<2048, 256, 0, stream>>>(acc, OUT_ELEMS);
    }
}